// Round 3
// baseline (52.358 us; speedup 1.0000x reference)
//
#include <hip/hip_runtime.h>
#include <hip/hip_bf16.h>

// LocalPPM: B=4, C=256, H=W=56, R=2 (5x5 -> K2=25), TOPK=10, TAU=0.1, EPS=1e-8
// out = x + gamma * sum_k softmax_top10(cos_sim(center, neighbor_k)/TAU) * neighbor_k
//
// Symmetry: dot(p, +o) == dot(p+o, -o); only 13 offsets k=0..12 computed
// (dy=-2,-1 full rows; dy=0, dx<=0); k_wts mirrors the rest.
//
// ws layout: dot[B][13][3136] floats (652 KB), then wts[B][3136][32] floats
// (pixel-major, 25 used + 7 pad for 128B alignment).

#define PX 3136   // 56*56
#define CS 3136   // channel plane stride (H*W)

// Single pass over x: 13 accumulators. block 512 = 32 px x 16 ch-chunks (16 ch).
// grid (98, 4) -> 392 blocks x 8 waves = 3136 waves.
__global__ __launch_bounds__(512) void k_dot(const float* __restrict__ x,
                                             float* __restrict__ dot) {
    const int px = threadIdx.x & 31;
    const int ck = threadIdx.x >> 5;               // 0..15 channel chunk (16 ch)
    const int p  = blockIdx.x * 32 + px;
    const int b  = blockIdx.y;
    const int h  = p / 56;
    const int w  = p - h * 56;

    const bool vm2 = (h >= 2), vm1 = (h >= 1);
    const bool cv0 = (w >= 2), cv1 = (w >= 1), cv3 = (w <= 54), cv4 = (w <= 53);

    const float* xb  = x + (size_t)b * 256 * CS + (size_t)ck * 16 * CS;
    const float* cp  = xb + p;        // center (row h, col w)
    const float* pr2 = cp - 112;      // row h-2
    const float* pr1 = cp - 56;       // row h-1

    float a[13];
    #pragma unroll
    for (int i = 0; i < 13; ++i) a[i] = 0.f;

    #pragma unroll 4
    for (int c = 0; c < 16; ++c) {
        const int o = c * CS;
        const float ctr = cp[o];
        float n;
        n = (vm2 && cv0) ? pr2[o - 2] : 0.f; a[0]  = fmaf(ctr, n, a[0]);
        n = (vm2 && cv1) ? pr2[o - 1] : 0.f; a[1]  = fmaf(ctr, n, a[1]);
        n =  vm2         ? pr2[o    ] : 0.f; a[2]  = fmaf(ctr, n, a[2]);
        n = (vm2 && cv3) ? pr2[o + 1] : 0.f; a[3]  = fmaf(ctr, n, a[3]);
        n = (vm2 && cv4) ? pr2[o + 2] : 0.f; a[4]  = fmaf(ctr, n, a[4]);
        n = (vm1 && cv0) ? pr1[o - 2] : 0.f; a[5]  = fmaf(ctr, n, a[5]);
        n = (vm1 && cv1) ? pr1[o - 1] : 0.f; a[6]  = fmaf(ctr, n, a[6]);
        n =  vm1         ? pr1[o    ] : 0.f; a[7]  = fmaf(ctr, n, a[7]);
        n = (vm1 && cv3) ? pr1[o + 1] : 0.f; a[8]  = fmaf(ctr, n, a[8]);
        n = (vm1 && cv4) ? pr1[o + 2] : 0.f; a[9]  = fmaf(ctr, n, a[9]);
        n =  cv0         ? cp [o - 2] : 0.f; a[10] = fmaf(ctr, n, a[10]);
        n =  cv1         ? cp [o - 1] : 0.f; a[11] = fmaf(ctr, n, a[11]);
        a[12] = fmaf(ctr, ctr, a[12]);
    }

    __shared__ float part[16][13][32];             // 26.6 KB
    #pragma unroll
    for (int i = 0; i < 13; ++i) part[ck][i][px] = a[i];
    __syncthreads();

    if (threadIdx.x < 13 * 32) {
        const int acc = threadIdx.x >> 5, pp = threadIdx.x & 31;
        float s = 0.f;
        #pragma unroll
        for (int j = 0; j < 16; ++j) s += part[j][acc][pp];
        dot[((size_t)(b * 13 + acc)) * PX + blockIdx.x * 32 + pp] = s;
    }
}

__global__ void k_wts(const float* __restrict__ dot, float* __restrict__ wts) {
    const int p = blockIdx.x * 64 + threadIdx.x;
    const int b = blockIdx.y;
    const int h = p / 56;
    const int w = p - h * 56;
    const float* db = dot + (size_t)b * 13 * PX;

    const float cn = sqrtf(db[12 * PX + p]);

    float s[25];
    #pragma unroll
    for (int k = 0; k < 25; ++k) {
        const int dy = k / 5 - 2, dx = k % 5 - 2;
        const int rr = h + dy, cc = w + dx;
        const bool v = (rr >= 0) && (rr < 56) && (cc >= 0) && (cc < 56);
        float d = 0.f, n2 = 0.f;
        if (v) {
            const int q = rr * 56 + cc;
            n2 = db[12 * PX + q];
            d  = (k <= 12) ? db[k * PX + p] : db[(24 - k) * PX + q];
        }
        s[k] = d / fmaxf(sqrtf(n2) * cn, 1e-8f) * 10.f;
    }

    float m = s[0];
    #pragma unroll
    for (int k = 1; k < 25; ++k) m = fmaxf(m, s[k]);

    // exact top-10 with JAX tie-break (value desc, index asc)
    float e[25];
    float denom = 0.f;
    #pragma unroll
    for (int k = 0; k < 25; ++k) {
        int rank = 0;
        #pragma unroll
        for (int j = 0; j < 25; ++j) {
            rank += (int)((s[j] > s[k]) || ((s[j] == s[k]) && (j < k)));
        }
        e[k] = (rank < 10) ? __expf(s[k] - m) : 0.f;
        denom += e[k];
    }
    const float inv = 1.f / denom;

    float* wb = wts + ((size_t)b * PX + p) * 32;   // 128B-aligned per pixel
    #pragma unroll
    for (int k4 = 0; k4 < 6; ++k4) {
        *(float4*)(wb + k4 * 4) = make_float4(e[k4*4+0] * inv, e[k4*4+1] * inv,
                                              e[k4*4+2] * inv, e[k4*4+3] * inv);
    }
    wb[24] = e[24] * inv;
}

__global__ void k_out(const float* __restrict__ x, const float* __restrict__ wts,
                      const float* __restrict__ gptr, float* __restrict__ out) {
    const int p  = blockIdx.x * 64 + threadIdx.x;
    const int cg = blockIdx.y;                     // 0..31, 8 channels each
    const int b  = blockIdx.z;
    const int h  = p / 56;
    const int w  = p - h * 56;
    const float g = *gptr;

    float wk[25];
    const float* wb = wts + ((size_t)b * PX + p) * 32;
    #pragma unroll
    for (int k4 = 0; k4 < 6; ++k4) {
        const float4 q = *(const float4*)(wb + k4 * 4);
        wk[k4*4+0] = q.x; wk[k4*4+1] = q.y; wk[k4*4+2] = q.z; wk[k4*4+3] = q.w;
    }
    wk[24] = wb[24];

    const float* xb = x   + ((size_t)b * 256 + cg * 8) * CS;
    float*       ob = out + ((size_t)b * 256 + cg * 8) * CS;

    #pragma unroll 2
    for (int ci = 0; ci < 8; ++ci) {
        const float* xp = xb + ci * CS;
        float y = 0.f;
        #pragma unroll
        for (int k = 0; k < 25; ++k) {
            const int dy = k / 5 - 2, dx = k % 5 - 2;
            const int rr = h + dy, cc = w + dx;
            const bool v = (rr >= 0) && (rr < 56) && (cc >= 0) && (cc < 56);
            const float xv = v ? xp[p + dy * 56 + dx] : 0.f;
            y = fmaf(wk[k], xv, y);
        }
        ob[ci * CS + p] = xp[p] + g * y;
    }
}

extern "C" void kernel_launch(void* const* d_in, const int* in_sizes, int n_in,
                              void* d_out, int out_size, void* d_ws, size_t ws_size,
                              hipStream_t stream) {
    const float* x     = (const float*)d_in[0];
    const float* gamma = (const float*)d_in[1];
    float* out = (float*)d_out;

    float* dot = (float*)d_ws;                 // [4][13][3136]
    float* wts = dot + 4 * 13 * PX;            // [4][3136][32]

    k_dot<<<dim3(98, 4), 512, 0, stream>>>(x, dot);
    k_wts<<<dim3(49, 4), 64, 0, stream>>>(dot, wts);
    k_out<<<dim3(49, 32, 4), 64, 0, stream>>>(x, wts, gamma, out);
}

// Round 4
// 41.340 us; speedup vs baseline: 1.2665x; 1.2665x over previous
//
#include <hip/hip_runtime.h>
#include <hip/hip_bf16.h>

// LocalPPM: B=4, C=256, H=W=56, R=2 (5x5 -> K2=25), TOPK=10, TAU=0.1, EPS=1e-8
// out = x + gamma * sum_k softmax_top10(cos_sim(center, neighbor_k)/TAU) * neighbor_k
//
// Symmetry: dot(p, +o) == dot(p+o, -o); only 13 offsets k=0..12 computed
// (dy=-2,-1 full rows; dy=0, dx<=0); k_fused mirrors the rest.
//
// Two kernels: k_dot -> dot[B][13][3136]; k_fused computes weights in LDS
// (top-10 masked softmax) and immediately accumulates the 25-tap weighted sum
// over all 256 channels. No wts round-trip, no tiny-grid softmax kernel.

#define PX 3136   // 56*56
#define CS 3136   // channel plane stride (H*W)

// Single pass over x: 13 accumulators. block 512 = 32 px x 16 ch-chunks (16 ch).
// grid (98, 4) -> 392 blocks x 8 waves = 3136 waves.
__global__ __launch_bounds__(512) void k_dot(const float* __restrict__ x,
                                             float* __restrict__ dot) {
    const int px = threadIdx.x & 31;
    const int ck = threadIdx.x >> 5;               // 0..15 channel chunk (16 ch)
    const int p  = blockIdx.x * 32 + px;
    const int b  = blockIdx.y;
    const int h  = p / 56;
    const int w  = p - h * 56;

    const bool vm2 = (h >= 2), vm1 = (h >= 1);
    const bool cv0 = (w >= 2), cv1 = (w >= 1), cv3 = (w <= 54), cv4 = (w <= 53);

    const float* xb  = x + (size_t)b * 256 * CS + (size_t)ck * 16 * CS;
    const float* cp  = xb + p;        // center (row h, col w)
    const float* pr2 = cp - 112;      // row h-2
    const float* pr1 = cp - 56;       // row h-1

    float a[13];
    #pragma unroll
    for (int i = 0; i < 13; ++i) a[i] = 0.f;

    #pragma unroll 4
    for (int c = 0; c < 16; ++c) {
        const int o = c * CS;
        const float ctr = cp[o];
        float n;
        n = (vm2 && cv0) ? pr2[o - 2] : 0.f; a[0]  = fmaf(ctr, n, a[0]);
        n = (vm2 && cv1) ? pr2[o - 1] : 0.f; a[1]  = fmaf(ctr, n, a[1]);
        n =  vm2         ? pr2[o    ] : 0.f; a[2]  = fmaf(ctr, n, a[2]);
        n = (vm2 && cv3) ? pr2[o + 1] : 0.f; a[3]  = fmaf(ctr, n, a[3]);
        n = (vm2 && cv4) ? pr2[o + 2] : 0.f; a[4]  = fmaf(ctr, n, a[4]);
        n = (vm1 && cv0) ? pr1[o - 2] : 0.f; a[5]  = fmaf(ctr, n, a[5]);
        n = (vm1 && cv1) ? pr1[o - 1] : 0.f; a[6]  = fmaf(ctr, n, a[6]);
        n =  vm1         ? pr1[o    ] : 0.f; a[7]  = fmaf(ctr, n, a[7]);
        n = (vm1 && cv3) ? pr1[o + 1] : 0.f; a[8]  = fmaf(ctr, n, a[8]);
        n = (vm1 && cv4) ? pr1[o + 2] : 0.f; a[9]  = fmaf(ctr, n, a[9]);
        n =  cv0         ? cp [o - 2] : 0.f; a[10] = fmaf(ctr, n, a[10]);
        n =  cv1         ? cp [o - 1] : 0.f; a[11] = fmaf(ctr, n, a[11]);
        a[12] = fmaf(ctr, ctr, a[12]);
    }

    __shared__ float part[16][13][32];             // 26.6 KB
    #pragma unroll
    for (int i = 0; i < 13; ++i) part[ck][i][px] = a[i];
    __syncthreads();

    if (threadIdx.x < 13 * 32) {
        const int acc = threadIdx.x >> 5, pp = threadIdx.x & 31;
        float s = 0.f;
        #pragma unroll
        for (int j = 0; j < 16; ++j) s += part[j][acc][pp];
        dot[((size_t)(b * 13 + acc)) * PX + blockIdx.x * 32 + pp] = s;
    }
}

// Fused weights + output. block 512 = 32 px x 16 ch-subgroups (16 ch each).
// grid (98, 4). Phase 1: 800 (px,k) items -> s in LDS; rank/top-10/exp; inv.
// Phase 2: per-thread 16 channels x 25 taps weighted accumulation.
__global__ __launch_bounds__(512) void k_fused(const float* __restrict__ x,
                                               const float* __restrict__ dot,
                                               const float* __restrict__ gptr,
                                               float* __restrict__ out) {
    const int tid   = threadIdx.x;
    const int pbase = blockIdx.x * 32;
    const int b     = blockIdx.y;
    const float* db = dot + (size_t)b * 13 * PX;

    __shared__ float s_lds[32][25];
    __shared__ float e_lds[32][25];
    __shared__ float inv_lds[32];

    // ---- phase 1a: sims into LDS (800 items over 512 threads) ----
    #pragma unroll
    for (int i = tid; i < 800; i += 512) {
        const int px = i / 25, k = i - px * 25;
        const int p = pbase + px;
        const int h = p / 56, w = p - (p / 56) * 56;
        const int dy = k / 5 - 2, dx = k % 5 - 2;
        const int rr = h + dy, cc = w + dx;
        const bool v = (rr >= 0) && (rr < 56) && (cc >= 0) && (cc < 56);
        float d = 0.f, n2 = 0.f;
        if (v) {
            const int q = rr * 56 + cc;
            n2 = db[12 * PX + q];
            d  = (k <= 12) ? db[k * PX + p] : db[(24 - k) * PX + q];
        }
        const float cn = sqrtf(db[12 * PX + p]);
        s_lds[px][k] = d / fmaxf(sqrtf(n2) * cn, 1e-8f) * 10.f;
    }
    __syncthreads();

    // ---- phase 1b: rank (exact top-10, JAX tie-break) + max + exp ----
    #pragma unroll
    for (int i = tid; i < 800; i += 512) {
        const int px = i / 25, k = i - px * 25;
        const float sk = s_lds[px][k];
        int rank = 0;
        float m = sk;
        #pragma unroll
        for (int j = 0; j < 25; ++j) {
            const float sj = s_lds[px][j];
            rank += (int)((sj > sk) || ((sj == sk) && (j < k)));
            m = fmaxf(m, sj);
        }
        e_lds[px][k] = (rank < 10) ? __expf(sk - m) : 0.f;
    }
    __syncthreads();

    // ---- phase 1c: per-pixel denom ----
    if (tid < 32) {
        float denom = 0.f;
        #pragma unroll
        for (int k = 0; k < 25; ++k) denom += e_lds[tid][k];
        inv_lds[tid] = 1.f / denom;
    }
    __syncthreads();

    // ---- phase 2: weighted accumulation over channels ----
    const int px  = tid & 31;
    const int sub = tid >> 5;                      // 0..15, 16 channels each
    const int p   = pbase + px;
    const int h   = p / 56;
    const int w   = p - h * 56;
    const float g = *gptr;

    const float inv = inv_lds[px];
    float wk[25];
    #pragma unroll
    for (int k = 0; k < 25; ++k) wk[k] = e_lds[px][k] * inv;

    const float* xb = x   + ((size_t)b * 256 + sub * 16) * CS;
    float*       ob = out + ((size_t)b * 256 + sub * 16) * CS;

    #pragma unroll 2
    for (int ci = 0; ci < 16; ++ci) {
        const float* xp = xb + ci * CS;
        float y = 0.f;
        #pragma unroll
        for (int k = 0; k < 25; ++k) {
            const int dy = k / 5 - 2, dx = k % 5 - 2;
            const int rr = h + dy, cc = w + dx;
            const bool v = (rr >= 0) && (rr < 56) && (cc >= 0) && (cc < 56);
            const float xv = v ? xp[p + dy * 56 + dx] : 0.f;
            y = fmaf(wk[k], xv, y);
        }
        ob[ci * CS + p] = xp[p] + g * y;
    }
}

extern "C" void kernel_launch(void* const* d_in, const int* in_sizes, int n_in,
                              void* d_out, int out_size, void* d_ws, size_t ws_size,
                              hipStream_t stream) {
    const float* x     = (const float*)d_in[0];
    const float* gamma = (const float*)d_in[1];
    float* out = (float*)d_out;

    float* dot = (float*)d_ws;                 // [4][13][3136]

    k_dot<<<dim3(98, 4), 512, 0, stream>>>(x, dot);
    k_fused<<<dim3(98, 4), 512, 0, stream>>>(x, dot, gamma, out);
}